// Round 2
// baseline (94.187 us; speedup 1.0000x reference)
//
#include <hip/hip_runtime.h>
#include <hip/hip_bf16.h>
#include <hip/hip_cooperative_groups.h>

namespace cg = cooperative_groups;

// Problem constants (B=4, D=128, N=512, fp32)
#define PB 4
#define PD 128
#define PN 512
#define NTILE 64              // n-columns per block tile
#define OTILE 16              // output rows per block tile
#define NT (PN / NTILE)       // 8 n-tiles
#define OT (PD / OTILE)       // 8 o-tiles

// ---------------- Fused cooperative kernel ----------------
// grid = 256 blocks (1/CU), block = 512 threads (8 waves, 2 rows/wave).
// Phase 1: A = W1@x, C = W2@x + b on a [16 x 64] tile; G = C - A kept in
// registers; per-tile row maxes of A -> pmax (device-scope atomic stores).
// grid.sync(). Phase 2: final row max from 8 partials; out = relu(G + max).
__global__ __launch_bounds__(512) void gcn_fused(
    const float* __restrict__ x, const float* __restrict__ W1,
    const float* __restrict__ W2, const float* __restrict__ bias,
    float* __restrict__ out, float* __restrict__ pmax) {
  const int bid = blockIdx.x;
  const int nt = bid % NT;
  const int ot = (bid / NT) % OT;
  const int b = bid / (NT * OT);

  __shared__ float xs[PD][NTILE];       // 32 KB
  __shared__ float4 w1s[OTILE][PD / 4]; // 8 KB
  __shared__ float4 w2s[OTILE][PD / 4]; // 8 KB

  const int tid = threadIdx.x;

  // Stage x tile [128 x 64] and W tiles [16 x 128] x2, coalesced float4.
  {
    const size_t xbase = (size_t)b * PD * PN + (size_t)nt * NTILE;
    for (int i = tid; i < PD * (NTILE / 4); i += 512) {
      const int d = i >> 4;
      const int c = i & 15;
      ((float4*)&xs[d][0])[c] = *(const float4*)(x + xbase + (size_t)d * PN + c * 4);
    }
    for (int i = tid; i < OTILE * (PD / 4); i += 512) {
      const int r = i >> 5;
      const int c = i & 31;
      w1s[r][c] = *(const float4*)(W1 + (size_t)(ot * OTILE + r) * PD + c * 4);
      w2s[r][c] = *(const float4*)(W2 + (size_t)(ot * OTILE + r) * PD + c * 4);
    }
  }
  __syncthreads();

  const int lane = tid & 63;
  const int w = tid >> 6;        // wave 0..7
  const int o0 = w * 2;          // 2 rows per wave

  float accA[2] = {0.f, 0.f};
  float accC[2];
#pragma unroll
  for (int k = 0; k < 2; ++k) accC[k] = bias[ot * OTILE + o0 + k];

  for (int dc = 0; dc < PD / 4; ++dc) {
    const int d = dc * 4;
    const float xv0 = xs[d + 0][lane];
    const float xv1 = xs[d + 1][lane];
    const float xv2 = xs[d + 2][lane];
    const float xv3 = xs[d + 3][lane];
#pragma unroll
    for (int k = 0; k < 2; ++k) {
      const float4 w1v = w1s[o0 + k][dc];   // broadcast b128 read
      const float4 w2v = w2s[o0 + k][dc];
      accA[k] = fmaf(w1v.x, xv0, accA[k]);
      accA[k] = fmaf(w1v.y, xv1, accA[k]);
      accA[k] = fmaf(w1v.z, xv2, accA[k]);
      accA[k] = fmaf(w1v.w, xv3, accA[k]);
      accC[k] = fmaf(w2v.x, xv0, accC[k]);
      accC[k] = fmaf(w2v.y, xv1, accC[k]);
      accC[k] = fmaf(w2v.z, xv2, accC[k]);
      accC[k] = fmaf(w2v.w, xv3, accC[k]);
    }
  }

  // Wave-wide max over the 64 n-lanes for each of this wave's 2 rows.
  const int row0 = b * PD + ot * OTILE + o0;   // global row index (b*D + d)
#pragma unroll
  for (int k = 0; k < 2; ++k) {
    float v = accA[k];
#pragma unroll
    for (int off = 32; off > 0; off >>= 1)
      v = fmaxf(v, __shfl_xor(v, off));
    if (lane == 0)
      __hip_atomic_store(&pmax[(size_t)(row0 + k) * NT + nt], v,
                         __ATOMIC_RELAXED, __HIP_MEMORY_SCOPE_AGENT);
  }

  float g[2] = {accC[0] - accA[0], accC[1] - accA[1]};

  __threadfence();           // device-scope release for pmax
  cg::this_grid().sync();

  // Phase 2: final row max from 8 partials; write out = relu(G + max).
#pragma unroll
  for (int k = 0; k < 2; ++k) {
    float mv = -INFINITY;
#pragma unroll
    for (int t = 0; t < NT; ++t)
      mv = fmaxf(mv, __hip_atomic_load(&pmax[(size_t)(row0 + k) * NT + t],
                                       __ATOMIC_RELAXED, __HIP_MEMORY_SCOPE_AGENT));
    out[(size_t)(row0 + k) * PN + (size_t)nt * NTILE + lane] =
        fmaxf(g[k] + mv, 0.f);
  }
}

// ---------------- Fallback: validated 2-kernel path ----------------
__global__ __launch_bounds__(256) void gcn_k1(
    const float* __restrict__ x, const float* __restrict__ W1,
    const float* __restrict__ W2, const float* __restrict__ bias,
    float* __restrict__ G, float* __restrict__ pmax) {
  const int bid = blockIdx.x;
  const int nt = bid % NT;
  const int ot = (bid / NT) % OT;
  const int b = bid / (NT * OT);

  __shared__ float xs[PD][NTILE];
  __shared__ float4 w1s[OTILE][PD / 4];
  __shared__ float4 w2s[OTILE][PD / 4];

  const int tid = threadIdx.x;
  {
    const size_t xbase = (size_t)b * PD * PN + (size_t)nt * NTILE;
    for (int i = tid; i < PD * (NTILE / 4); i += 256) {
      const int d = i >> 4;
      const int c = i & 15;
      ((float4*)&xs[d][0])[c] = *(const float4*)(x + xbase + (size_t)d * PN + c * 4);
    }
    for (int i = tid; i < OTILE * (PD / 4); i += 256) {
      const int r = i >> 5;
      const int c = i & 31;
      w1s[r][c] = *(const float4*)(W1 + (size_t)(ot * OTILE + r) * PD + c * 4);
      w2s[r][c] = *(const float4*)(W2 + (size_t)(ot * OTILE + r) * PD + c * 4);
    }
  }
  __syncthreads();

  const int lane = tid & 63;
  const int w = tid >> 6;
  const int o0 = w * 4;

  float accA[4] = {0.f, 0.f, 0.f, 0.f};
  float accC[4];
#pragma unroll
  for (int k = 0; k < 4; ++k) accC[k] = bias[ot * OTILE + o0 + k];

  for (int dc = 0; dc < PD / 4; ++dc) {
    const int d = dc * 4;
    const float xv0 = xs[d + 0][lane];
    const float xv1 = xs[d + 1][lane];
    const float xv2 = xs[d + 2][lane];
    const float xv3 = xs[d + 3][lane];
#pragma unroll
    for (int k = 0; k < 4; ++k) {
      const float4 w1v = w1s[o0 + k][dc];
      const float4 w2v = w2s[o0 + k][dc];
      accA[k] = fmaf(w1v.x, xv0, accA[k]);
      accA[k] = fmaf(w1v.y, xv1, accA[k]);
      accA[k] = fmaf(w1v.z, xv2, accA[k]);
      accA[k] = fmaf(w1v.w, xv3, accA[k]);
      accC[k] = fmaf(w2v.x, xv0, accC[k]);
      accC[k] = fmaf(w2v.y, xv1, accC[k]);
      accC[k] = fmaf(w2v.z, xv2, accC[k]);
      accC[k] = fmaf(w2v.w, xv3, accC[k]);
    }
  }

  float m[4];
#pragma unroll
  for (int k = 0; k < 4; ++k) {
    float v = accA[k];
#pragma unroll
    for (int off = 32; off > 0; off >>= 1)
      v = fmaxf(v, __shfl_xor(v, off));
    m[k] = v;
  }

  const size_t gbase =
      (size_t)b * PD * PN + (size_t)(ot * OTILE + o0) * PN + (size_t)nt * NTILE;
#pragma unroll
  for (int k = 0; k < 4; ++k)
    G[gbase + (size_t)k * PN + lane] = accC[k] - accA[k];

  if (lane == 0) {
#pragma unroll
    for (int k = 0; k < 4; ++k)
      pmax[(size_t)(b * PD + ot * OTILE + o0 + k) * NT + nt] = m[k];
  }
}

__global__ __launch_bounds__(256) void gcn_k2(
    const float* __restrict__ G, const float* __restrict__ pmax,
    float* __restrict__ out) {
  const int tid = threadIdx.x;
  const int row = blockIdx.x * 2 + (tid >> 7);
  const int i = tid & 127;

  float mv = pmax[(size_t)row * NT];
#pragma unroll
  for (int t = 1; t < NT; ++t)
    mv = fmaxf(mv, pmax[(size_t)row * NT + t]);

  const float4 g = ((const float4*)G)[(size_t)row * (PN / 4) + i];
  float4 o;
  o.x = fmaxf(g.x + mv, 0.f);
  o.y = fmaxf(g.y + mv, 0.f);
  o.z = fmaxf(g.z + mv, 0.f);
  o.w = fmaxf(g.w + mv, 0.f);
  ((float4*)out)[(size_t)row * (PN / 4) + i] = o;
}

extern "C" void kernel_launch(void* const* d_in, const int* in_sizes, int n_in,
                              void* d_out, int out_size, void* d_ws, size_t ws_size,
                              hipStream_t stream) {
  const float* x = (const float*)d_in[0];
  const float* W1 = (const float*)d_in[1];
  const float* W2 = (const float*)d_in[2];
  const float* bias = (const float*)d_in[3];
  float* out = (float*)d_out;

  float* G = (float*)d_ws;                                           // 1 MB (fallback)
  float* pmax = (float*)((char*)d_ws + (size_t)PB * PD * PN * sizeof(float)); // 16 KB

  void* args[] = {(void*)&x, (void*)&W1, (void*)&W2, (void*)&bias,
                  (void*)&out, (void*)&pmax};
  hipError_t e = hipLaunchCooperativeKernel((const void*)gcn_fused,
                                            dim3(PB * OT * NT), dim3(512),
                                            args, 0, stream);
  if (e != hipSuccess) {
    // Fallback: validated two-kernel path.
    gcn_k1<<<dim3(PB * OT * NT), dim3(256), 0, stream>>>(x, W1, W2, bias, G, pmax);
    gcn_k2<<<dim3(PB * PD / 2), dim3(256), 0, stream>>>(G, pmax, out);
  }
}

// Round 3
// 11.910 us; speedup vs baseline: 7.9082x; 7.9082x over previous
//
#include <hip/hip_runtime.h>
#include <hip/hip_bf16.h>

// Problem constants (B=4, D=128, N=512, fp32)
#define PB 4
#define PD 128
#define PN 512

__device__ __forceinline__ float f4get(const float4& v, int k) {
  const float* p = (const float*)&v;
  return p[k];
}

// One block = 2 full output rows (all N columns) for one batch.
// grid = B * D/2 = 256 blocks, 256 threads (4 waves).
// Wave w owns n-quarter [w*128, w*128+128); lane owns 2 consecutive n.
// Each thread computes A = W1@x and Craw = W2@x for BOTH rows at its 2
// columns -> row max of A is block-local (shuffle + tiny LDS reduce), then
// out = relu(rowmax + Craw + bias - A). No second kernel, no grid sync.
__global__ __launch_bounds__(256) void gcn_one(
    const float* __restrict__ x, const float* __restrict__ W1,
    const float* __restrict__ W2, const float* __restrict__ bias,
    float* __restrict__ out) {
  const int bid = blockIdx.x;
  const int b = bid >> 6;              // batch 0..3
  const int r0 = (bid & 63) << 1;      // first of this block's 2 rows
  const int tid = threadIdx.x;
  const int lane = tid & 63;
  const int w = tid >> 6;              // wave 0..3 -> n-quarter

  __shared__ float4 ws[2][2][32];      // [mat][row][d-chunk] : 2 KB
  __shared__ float redmax[2][4];       // [row][wave]

  // Stage 4 W-rows (W1,W2 x 2 rows), one float4 per thread (tid < 128).
  if (tid < 128) {
    const int mat = tid >> 6;          // 0 = W1, 1 = W2
    const int r = (tid >> 5) & 1;
    const int c = tid & 31;
    const float* Wm = mat ? W2 : W1;
    ws[mat][r][c] = *(const float4*)(Wm + (size_t)(r0 + r) * PD + (c << 2));
  }
  __syncthreads();

  const int n0 = (w << 7) + (lane << 1);           // this thread's 2 columns
  const float* xp = x + (size_t)b * PD * PN + n0;

  float2 a0 = {0.f, 0.f}, a1 = {0.f, 0.f};         // A rows 0,1
  float2 c0 = {0.f, 0.f}, c1 = {0.f, 0.f};         // W2@x rows 0,1

#pragma unroll 4
  for (int dc = 0; dc < 32; ++dc) {
    const float4 w10 = ws[0][0][dc];   // broadcast b128 reads (conflict-free)
    const float4 w11 = ws[0][1][dc];
    const float4 w20 = ws[1][0][dc];
    const float4 w21 = ws[1][1][dc];
    float2 xv[4];
#pragma unroll
    for (int k = 0; k < 4; ++k)
      xv[k] = *(const float2*)(xp + (size_t)(dc * 4 + k) * PN);
#pragma unroll
    for (int k = 0; k < 4; ++k) {
      const float u10 = f4get(w10, k), u11 = f4get(w11, k);
      const float u20 = f4get(w20, k), u21 = f4get(w21, k);
      a0.x = fmaf(u10, xv[k].x, a0.x); a0.y = fmaf(u10, xv[k].y, a0.y);
      a1.x = fmaf(u11, xv[k].x, a1.x); a1.y = fmaf(u11, xv[k].y, a1.y);
      c0.x = fmaf(u20, xv[k].x, c0.x); c0.y = fmaf(u20, xv[k].y, c0.y);
      c1.x = fmaf(u21, xv[k].x, c1.x); c1.y = fmaf(u21, xv[k].y, c1.y);
    }
  }

  // Row max of A: lane-local (2) -> wave shuffle (64) -> cross-wave LDS (4).
  float m0 = fmaxf(a0.x, a0.y);
  float m1 = fmaxf(a1.x, a1.y);
#pragma unroll
  for (int off = 32; off > 0; off >>= 1) {
    m0 = fmaxf(m0, __shfl_xor(m0, off));
    m1 = fmaxf(m1, __shfl_xor(m1, off));
  }
  if (lane == 0) {
    redmax[0][w] = m0;
    redmax[1][w] = m1;
  }
  __syncthreads();
  const float M0 = fmaxf(fmaxf(redmax[0][0], redmax[0][1]),
                         fmaxf(redmax[0][2], redmax[0][3]));
  const float M1 = fmaxf(fmaxf(redmax[1][0], redmax[1][1]),
                         fmaxf(redmax[1][2], redmax[1][3]));
  const float b0 = bias[r0], b1 = bias[r0 + 1];

  float2 o0, o1;
  o0.x = fmaxf(M0 + c0.x + b0 - a0.x, 0.f);
  o0.y = fmaxf(M0 + c0.y + b0 - a0.y, 0.f);
  o1.x = fmaxf(M1 + c1.x + b1 - a1.x, 0.f);
  o1.y = fmaxf(M1 + c1.y + b1 - a1.y, 0.f);

  float* op = out + (size_t)(b * PD + r0) * PN + n0;
  *(float2*)op = o0;
  *(float2*)(op + PN) = o1;
}

extern "C" void kernel_launch(void* const* d_in, const int* in_sizes, int n_in,
                              void* d_out, int out_size, void* d_ws, size_t ws_size,
                              hipStream_t stream) {
  const float* x = (const float*)d_in[0];
  const float* W1 = (const float*)d_in[1];
  const float* W2 = (const float*)d_in[2];
  const float* bias = (const float*)d_in[3];
  float* out = (float*)d_out;

  gcn_one<<<dim3(PB * PD / 2), dim3(256), 0, stream>>>(x, W1, W2, bias, out);
}